// Round 7
// baseline (393.455 us; speedup 1.0000x reference)
//
#include <hip/hip_runtime.h>

#define B_  4
#define L_  1024
#define D_  512
#define H_  8
#define DK_ 64
#define BL_ (B_*L_)

typedef unsigned short us16;   // raw bf16 bits
typedef __attribute__((ext_vector_type(8))) short bf16x8;
typedef __attribute__((ext_vector_type(4))) float f32x4;

__device__ __forceinline__ float us2f(us16 u) {
  union { unsigned int i; float f; } x;
  x.i = ((unsigned int)u) << 16;
  return x.f;
}
__device__ __forceinline__ us16 f2us(float f) {
  union { float f; unsigned int i; } x;
  x.f = f;
  unsigned int r = x.i + 0x7FFFu + ((x.i >> 16) & 1u);  // RNE
  return (us16)(r >> 16);
}
__device__ __forceinline__ us16 cvt_us(float f) { return f2us(f); }
__device__ __forceinline__ us16 cvt_us(us16 u) { return u; }

#define MFMA(a, b, c) __builtin_amdgcn_mfma_f32_16x16x32_bf16(a, b, c, 0, 0, 0)

// ---------------------------------------------------------------------------
// Elementwise f32 -> bf16 (vectorized).
// ---------------------------------------------------------------------------
__global__ __launch_bounds__(256) void cvt_bf16(
    const float* __restrict__ src, us16* __restrict__ dst) {
  size_t i = ((size_t)blockIdx.x * 256 + threadIdx.x) * 4;
  float4 v = *(const float4*)(src + i);
  union { ushort4 v4; us16 u[4]; } o;
  o.u[0] = f2us(v.x); o.u[1] = f2us(v.y); o.u[2] = f2us(v.z); o.u[3] = f2us(v.w);
  *(ushort4*)(dst + i) = o.v4;
}

// ---------------------------------------------------------------------------
// Weight transpose+cvt: W f32 [512 k][512 n] -> Wt bf16 [n][k]. grid (8,8).
// ---------------------------------------------------------------------------
__global__ __launch_bounds__(256) void wtrans(
    const float* __restrict__ W, us16* __restrict__ Wt) {
  __shared__ us16 T[64][72];
  const int t = threadIdx.x;
  const int k0 = blockIdx.y * 64, n0 = blockIdx.x * 64;
  {
    int r = t >> 2, c = (t & 3) * 16;
    const float* src = W + (size_t)(k0 + r) * 512 + n0 + c;
    union { bf16x8 v; us16 u[8]; } p0, p1;
#pragma unroll
    for (int j = 0; j < 8; ++j) { p0.u[j] = f2us(src[j]); p1.u[j] = f2us(src[8 + j]); }
    *(bf16x8*)&T[r][c] = p0.v;
    *(bf16x8*)&T[r][c + 8] = p1.v;
  }
  __syncthreads();
  {
    int n = t >> 2, c = (t & 3) * 16;
    union { bf16x8 v; us16 u[8]; } p0, p1;
#pragma unroll
    for (int j = 0; j < 8; ++j) { p0.u[j] = T[c + j][n]; p1.u[j] = T[c + 8 + j][n]; }
    us16* dst = Wt + (size_t)(n0 + n) * 512 + k0 + c;
    *(bf16x8*)dst = p0.v;
    *(bf16x8*)(dst + 8) = p1.v;
  }
}

// ---------------------------------------------------------------------------
// Fast GEMM (big-ws path): C = A(bf16, Mx512) @ Wt(bf16 [n][k]) + bias(f32).
// BK=64, pure b128 staging. MODE 0: C bf16 [.][512]; 1: Vt [b][h][dk][kv]; 2: f32.
// ---------------------------------------------------------------------------
template <int MODE>
__global__ __launch_bounds__(256) void gemmA(
    const us16* __restrict__ A, const us16* __restrict__ Wt,
    const float* __restrict__ bias, void* __restrict__ Cout) {
  __shared__ us16 Al[64][72];
  __shared__ us16 Wl[64][72];
  const int tid = threadIdx.x;
  const int w = tid >> 6, lane = tid & 63;
  const int quad = lane >> 4, lc = lane & 15;
  const int row0 = blockIdx.y * 64, col0 = blockIdx.x * 64;
  const int sr = tid >> 2, sc = (tid & 3) * 16;
  f32x4 acc[4] = {};
  for (int k0 = 0; k0 < 512; k0 += 64) {
    const us16* as = A + (size_t)(row0 + sr) * 512 + k0 + sc;
    const us16* wsrc = Wt + (size_t)(col0 + sr) * 512 + k0 + sc;
    *(bf16x8*)&Al[sr][sc] = *(const bf16x8*)as;
    *(bf16x8*)&Al[sr][sc + 8] = *(const bf16x8*)(as + 8);
    *(bf16x8*)&Wl[sr][sc] = *(const bf16x8*)wsrc;
    *(bf16x8*)&Wl[sr][sc + 8] = *(const bf16x8*)(wsrc + 8);
    __syncthreads();
    bf16x8 a0 = *(const bf16x8*)&Al[w * 16 + lc][quad * 8];
    bf16x8 a1 = *(const bf16x8*)&Al[w * 16 + lc][32 + quad * 8];
#pragma unroll
    for (int ct = 0; ct < 4; ++ct) {
      bf16x8 b0 = *(const bf16x8*)&Wl[ct * 16 + lc][quad * 8];
      bf16x8 b1 = *(const bf16x8*)&Wl[ct * 16 + lc][32 + quad * 8];
      acc[ct] = MFMA(a0, b0, acc[ct]);
      acc[ct] = MFMA(a1, b1, acc[ct]);
    }
    __syncthreads();
  }
  const int orow = row0 + w * 16 + quad * 4;
#pragma unroll
  for (int ct = 0; ct < 4; ++ct) {
    const int col = col0 + ct * 16 + lc;
    const float bv = bias[col];
    if (MODE == 0) {
      us16* C = (us16*)Cout;
#pragma unroll
      for (int r = 0; r < 4; ++r)
        C[(size_t)(orow + r) * 512 + col] = f2us(acc[ct][r] + bv);
    } else if (MODE == 1) {
      us16* C = (us16*)Cout;
      const int h = col >> 6, dk = col & 63;
#pragma unroll
      for (int r = 0; r < 4; ++r) {
        const int grow = orow + r;
        const int b = grow >> 10, kv = grow & 1023;
        C[(((size_t)b * H_ + h) * DK_ + dk) * L_ + kv] = f2us(acc[ct][r] + bv);
      }
    } else {
      float* C = (float*)Cout;
#pragma unroll
      for (int r = 0; r < 4; ++r)
        C[(size_t)(orow + r) * 512 + col] = acc[ct][r] + bv;
    }
  }
}

// ---------------------------------------------------------------------------
// Fallback GEMM (round-6): A f32/us16, W f32 row-major, in-kernel transpose.
// ---------------------------------------------------------------------------
template <int MODE, typename TA>
__global__ __launch_bounds__(256) void gemm16(
    const TA* __restrict__ A, const float* __restrict__ W,
    const float* __restrict__ bias, void* __restrict__ Cout) {
  __shared__ us16 Al[64][56];
  __shared__ us16 Wl[64][56];
  const int tid = threadIdx.x;
  const int w = tid >> 6, lane = tid & 63;
  const int quad = lane >> 4, lc = lane & 15;
  const int row0 = blockIdx.y * 64, col0 = blockIdx.x * 64;
  f32x4 acc[4] = {};
  const int arow = tid >> 2, aks = (tid & 3) * 8;
  const int wk = tid & 31, wns = (tid >> 5) * 8;
  for (int k0 = 0; k0 < 512; k0 += 32) {
    {
      union { bf16x8 v; us16 u[8]; } pk;
      const TA* src = A + (size_t)(row0 + arow) * 512 + k0 + aks;
#pragma unroll
      for (int j = 0; j < 8; ++j) pk.u[j] = cvt_us(src[j]);
      *(bf16x8*)&Al[arow][aks] = pk.v;
    }
    {
      const float* src = W + (size_t)(k0 + wk) * 512 + col0 + wns;
#pragma unroll
      for (int j = 0; j < 8; ++j) Wl[wns + j][wk] = f2us(src[j]);
    }
    __syncthreads();
    bf16x8 af = *(const bf16x8*)&Al[w * 16 + lc][quad * 8];
#pragma unroll
    for (int ct = 0; ct < 4; ++ct) {
      bf16x8 bf = *(const bf16x8*)&Wl[ct * 16 + lc][quad * 8];
      acc[ct] = MFMA(af, bf, acc[ct]);
    }
    __syncthreads();
  }
  const int orow = row0 + w * 16 + quad * 4;
#pragma unroll
  for (int ct = 0; ct < 4; ++ct) {
    const int col = col0 + ct * 16 + lc;
    const float bv = bias[col];
    if (MODE == 0) {
      us16* C = (us16*)Cout;
#pragma unroll
      for (int r = 0; r < 4; ++r)
        C[(size_t)(orow + r) * 512 + col] = f2us(acc[ct][r] + bv);
    } else if (MODE == 1) {
      us16* C = (us16*)Cout;
      const int h = col >> 6, dk = col & 63;
#pragma unroll
      for (int r = 0; r < 4; ++r) {
        const int grow = orow + r;
        const int b = grow >> 10, kv = grow & 1023;
        C[(((size_t)b * H_ + h) * DK_ + dk) * L_ + kv] = f2us(acc[ct][r] + bv);
      }
    } else {
      float* C = (float*)Cout;
#pragma unroll
      for (int r = 0; r < 4; ++r)
        C[(size_t)(orow + r) * 512 + col] = acc[ct][r] + bv;
    }
  }
}

// ---------------------------------------------------------------------------
// Mask: m = sigmoid(QP.KP^T / sqrt(512)) -> f32. NT MFMA. (both paths)
// ---------------------------------------------------------------------------
__global__ __launch_bounds__(256) void mask16(
    const us16* __restrict__ QP, const us16* __restrict__ KP,
    float* __restrict__ Mout) {
  __shared__ us16 Al[64][56];
  __shared__ us16 Bl[64][56];
  const int tid = threadIdx.x;
  const int w = tid >> 6, lane = tid & 63;
  const int quad = lane >> 4, lc = lane & 15;
  const int b = blockIdx.z;
  const int row0 = blockIdx.y * 64, col0 = blockIdx.x * 64;
  const us16* Ab = QP + (size_t)b * L_ * D_;
  const us16* Bb = KP + (size_t)b * L_ * D_;
  f32x4 acc[4] = {};
  const int arow = tid >> 2, aks = (tid & 3) * 8;
  for (int k0 = 0; k0 < 512; k0 += 32) {
    *(bf16x8*)&Al[arow][aks] =
        *(const bf16x8*)(Ab + (size_t)(row0 + arow) * 512 + k0 + aks);
    *(bf16x8*)&Bl[arow][aks] =
        *(const bf16x8*)(Bb + (size_t)(col0 + arow) * 512 + k0 + aks);
    __syncthreads();
    bf16x8 af = *(const bf16x8*)&Al[w * 16 + lc][quad * 8];
#pragma unroll
    for (int ct = 0; ct < 4; ++ct) {
      bf16x8 bf = *(const bf16x8*)&Bl[ct * 16 + lc][quad * 8];
      acc[ct] = MFMA(af, bf, acc[ct]);
    }
    __syncthreads();
  }
  const float sc = 0.04419417382415922f;  // 1/sqrt(512)
  const int orow = row0 + w * 16 + quad * 4;
#pragma unroll
  for (int ct = 0; ct < 4; ++ct) {
    const int col = col0 + ct * 16 + lc;
#pragma unroll
    for (int r = 0; r < 4; ++r) {
      float x = acc[ct][r] * sc;
      Mout[((size_t)b * L_ + orow + r) * L_ + col] = 1.f / (1.f + __expf(-x));
    }
  }
}

// g[row] = sigmoid(query[row,:] . gate_w + gate_b)
__global__ __launch_bounds__(256) void gate_kernel(
    const float* __restrict__ query, const float* __restrict__ gw,
    const float* __restrict__ gb, float* __restrict__ g) {
  int row = blockIdx.x * 4 + (threadIdx.x >> 6);
  int lane = threadIdx.x & 63;
  float p = 0.f;
  for (int d = lane; d < D_; d += 64) p += query[(size_t)row * D_ + d] * gw[d];
#pragma unroll
  for (int off = 32; off; off >>= 1) p += __shfl_down(p, off);
  if (lane == 0) g[row] = 1.f / (1.f + __expf(-(p + gb[0])));
}

// ---------------------------------------------------------------------------
// Attention v2: QK^T -> scores stay in REGISTERS (64 f32/thread); double
// softmax via 4 cross-wave LDS reduction rounds; P bf16 in small LDS; PV mfma.
// LDS ~36 KB -> 4 blocks/CU. O written in place over Qp (same-cell only).
// ---------------------------------------------------------------------------
__global__ __launch_bounds__(256, 3) void attn2(
    const us16* Qp, const us16* __restrict__ Kp,
    const us16* __restrict__ Vt, const float* __restrict__ Mm,
    const float* __restrict__ gbuf, us16* O) {
  __shared__ us16 Ql[16][72];
  __shared__ us16 P[16 * 1032];
  __shared__ float red[4][4][16];   // [round][wave][row]
  const int tid = threadIdx.x;
  const int w = tid >> 6, lane = tid & 63;
  const int quad = lane >> 4, lc = lane & 15;
  const int b = blockIdx.z, h = blockIdx.y, q0 = blockIdx.x * 16;

  if (tid < 128) {
    int r = tid >> 3, ks = (tid & 7) * 8;
    *(bf16x8*)&Ql[r][ks] =
        *(const bf16x8*)(Qp + (size_t)(b * L_ + q0 + r) * D_ + h * DK_ + ks);
  }
  __syncthreads();

  bf16x8 qa0 = *(const bf16x8*)&Ql[lc][quad * 8];
  bf16x8 qa1 = *(const bf16x8*)&Ql[lc][32 + quad * 8];

  // QK^T: thread holds s[kt][r] = S[row=quad*4+r][col=kt*64+w*16+lc]
  const us16* Kbase = Kp + (size_t)b * L_ * D_ + h * DK_;
  float s[16][4];
#pragma unroll 4
  for (int kt = 0; kt < 16; ++kt) {
    const us16* kr = Kbase + (size_t)(kt * 64 + w * 16 + lc) * D_;
    bf16x8 b0 = *(const bf16x8*)(kr + quad * 8);
    bf16x8 b1 = *(const bf16x8*)(kr + 32 + quad * 8);
    f32x4 a = {};
    a = MFMA(qa0, b0, a);
    a = MFMA(qa1, b1, a);
#pragma unroll
    for (int r = 0; r < 4; ++r) s[kt][r] = a[r] * 0.125f;  // 1/sqrt(64)
  }

  // ---- round 0: first max
  float mx[4];
#pragma unroll
  for (int r = 0; r < 4; ++r) {
    float m = s[0][r];
#pragma unroll
    for (int kt = 1; kt < 16; ++kt) m = fmaxf(m, s[kt][r]);
#pragma unroll
    for (int off = 1; off < 16; off <<= 1) m = fmaxf(m, __shfl_xor(m, off));
    mx[r] = m;
  }
  if (lc == 0)
#pragma unroll
    for (int r = 0; r < 4; ++r) red[0][w][quad * 4 + r] = mx[r];
  __syncthreads();
#pragma unroll
  for (int r = 0; r < 4; ++r) {
    const int row = quad * 4 + r;
    mx[r] = fmaxf(fmaxf(red[0][0][row], red[0][1][row]),
                  fmaxf(red[0][2][row], red[0][3][row]));
  }

  // ---- round 1: exp + first sum
  float sm[4];
#pragma unroll
  for (int r = 0; r < 4; ++r) {
    float t = 0.f;
#pragma unroll
    for (int kt = 0; kt < 16; ++kt) { s[kt][r] = __expf(s[kt][r] - mx[r]); t += s[kt][r]; }
#pragma unroll
    for (int off = 1; off < 16; off <<= 1) t += __shfl_xor(t, off);
    sm[r] = t;
  }
  if (lc == 0)
#pragma unroll
    for (int r = 0; r < 4; ++r) red[1][w][quad * 4 + r] = sm[r];
  __syncthreads();
  float inv[4];
#pragma unroll
  for (int r = 0; r < 4; ++r) {
    const int row = quad * 4 + r;
    inv[r] = 1.f / (red[1][0][row] + red[1][1][row] + red[1][2][row] + red[1][3][row]);
  }

  // ---- calibration: c = p * (g + (1-g)*exp(1-m)), then round 2: second max
  float gq[4];
#pragma unroll
  for (int r = 0; r < 4; ++r) gq[r] = gbuf[b * L_ + q0 + quad * 4 + r];
#pragma unroll
  for (int r = 0; r < 4; ++r) {
    const float* mrow = Mm + (size_t)(b * L_ + q0 + quad * 4 + r) * L_;
    float m2 = -1e30f;
#pragma unroll
    for (int kt = 0; kt < 16; ++kt) {
      float mval = mrow[kt * 64 + w * 16 + lc];
      float c = s[kt][r] * inv[r] * (gq[r] + (1.f - gq[r]) * __expf(1.f - mval));
      s[kt][r] = c;
      m2 = fmaxf(m2, c);
    }
#pragma unroll
    for (int off = 1; off < 16; off <<= 1) m2 = fmaxf(m2, __shfl_xor(m2, off));
    mx[r] = m2;
  }
  if (lc == 0)
#pragma unroll
    for (int r = 0; r < 4; ++r) red[2][w][quad * 4 + r] = mx[r];
  __syncthreads();
#pragma unroll
  for (int r = 0; r < 4; ++r) {
    const int row = quad * 4 + r;
    mx[r] = fmaxf(fmaxf(red[2][0][row], red[2][1][row]),
                  fmaxf(red[2][2][row], red[2][3][row]));
  }

  // ---- round 3: second exp + sum
#pragma unroll
  for (int r = 0; r < 4; ++r) {
    float t = 0.f;
#pragma unroll
    for (int kt = 0; kt < 16; ++kt) { s[kt][r] = __expf(s[kt][r] - mx[r]); t += s[kt][r]; }
#pragma unroll
    for (int off = 1; off < 16; off <<= 1) t += __shfl_xor(t, off);
    sm[r] = t;
  }
  if (lc == 0)
#pragma unroll
    for (int r = 0; r < 4; ++r) red[3][w][quad * 4 + r] = sm[r];
  __syncthreads();
#pragma unroll
  for (int r = 0; r < 4; ++r) {
    const int row = quad * 4 + r;
    inv[r] = 1.f / (red[3][0][row] + red[3][1][row] + red[3][2][row] + red[3][3][row]);
  }

  // ---- P (bf16) to LDS, A-operand layout [row][kv], stride 1032
#pragma unroll
  for (int kt = 0; kt < 16; ++kt)
#pragma unroll
    for (int r = 0; r < 4; ++r)
      P[(quad * 4 + r) * 1032 + kt * 64 + w * 16 + lc] = f2us(s[kt][r] * inv[r]);
  __syncthreads();

  // ---- PV: wave w computes dk slice w*16+lc
  const us16* Vb = Vt + (size_t)(b * H_ + h) * DK_ * L_;  // [dk][kv]
  f32x4 oacc = {};
  for (int kv = 0; kv < L_; kv += 32) {
    bf16x8 pa = *(const bf16x8*)&P[lc * 1032 + kv + quad * 8];
    bf16x8 vb = *(const bf16x8*)(Vb + (size_t)(w * 16 + lc) * L_ + kv + quad * 8);
    oacc = MFMA(pa, vb, oacc);
  }
#pragma unroll
  for (int r = 0; r < 4; ++r)
    O[(size_t)(b * L_ + q0 + quad * 4 + r) * D_ + h * DK_ + w * 16 + lc] =
        f2us(oacc[r]);
}

extern "C" void kernel_launch(void* const* d_in, const int* in_sizes, int n_in,
                              void* d_out, int out_size, void* d_ws, size_t ws_size,
                              hipStream_t stream) {
  const float* query   = (const float*)d_in[0];
  const float* key     = (const float*)d_in[1];
  const float* value   = (const float*)d_in[2];
  const float* wq_w    = (const float*)d_in[3];
  const float* wq_b    = (const float*)d_in[4];
  const float* wk_w    = (const float*)d_in[5];
  const float* wk_b    = (const float*)d_in[6];
  const float* wv_w    = (const float*)d_in[7];
  const float* wv_b    = (const float*)d_in[8];
  const float* dense_w = (const float*)d_in[9];
  const float* dense_b = (const float*)d_in[10];
  const float* gate_w  = (const float*)d_in[11];
  const float* gate_b  = (const float*)d_in[12];
  const float* mp_wq_w = (const float*)d_in[13];
  const float* mp_wq_b = (const float*)d_in[14];
  const float* mp_wk_w = (const float*)d_in[15];
  const float* mp_wk_b = (const float*)d_in[16];

  const size_t RSZ = (size_t)BL_ * D_;   // 2,097,152 elems
  const size_t WSZ = (size_t)D_ * D_;    // 262,144 elems
  us16* R0 = (us16*)d_ws;
  us16* R1 = R0 + RSZ;

  float* out0 = (float*)d_out;                 // final out f32 (8 MB)
  float* outm = out0 + (size_t)B_ * L_ * D_;   // m f32 (16 MB)
  us16*  Vt   = (us16*)d_out;                  // V^T bf16 in out bytes [0,4M)
  float* gbuf = (float*)((char*)d_out + (4u << 20));

  dim3 blk(256);
  dim3 gproj(8, 64);
  dim3 gmask(16, 16, B_);
  dim3 gattn(L_ / 16, H_, B_);

  if (ws_size >= ((size_t)24 << 20)) {
    // -------- big-ws path: pre-cvt inputs + pre-transposed weights --------
    us16* Wt0 = R1 + RSZ;            // 6 x 512KB at ws+8M
    us16* mpq_t = Wt0;
    us16* mpk_t = Wt0 + WSZ;
    us16* wq_t  = Wt0 + 2 * WSZ;
    us16* wk_t  = Wt0 + 3 * WSZ;
    us16* wv_t  = Wt0 + 4 * WSZ;
    us16* dw_t  = Wt0 + 5 * WSZ;
    us16* Qbf = Wt0 + 6 * WSZ;       // ws+11M
    us16* Kbf = Qbf + RSZ;           // ws+15M
    us16* Vbf = Kbf + RSZ;           // ws+19M .. 23M

    dim3 gcvt(RSZ / (256 * 4));
    dim3 gwt(8, 8);
    hipLaunchKernelGGL(cvt_bf16, gcvt, blk, 0, stream, query, Qbf);
    hipLaunchKernelGGL(cvt_bf16, gcvt, blk, 0, stream, key,   Kbf);
    hipLaunchKernelGGL(cvt_bf16, gcvt, blk, 0, stream, value, Vbf);
    hipLaunchKernelGGL(wtrans, gwt, blk, 0, stream, mp_wq_w, mpq_t);
    hipLaunchKernelGGL(wtrans, gwt, blk, 0, stream, mp_wk_w, mpk_t);
    hipLaunchKernelGGL(wtrans, gwt, blk, 0, stream, wq_w, wq_t);
    hipLaunchKernelGGL(wtrans, gwt, blk, 0, stream, wk_w, wk_t);
    hipLaunchKernelGGL(wtrans, gwt, blk, 0, stream, wv_w, wv_t);
    hipLaunchKernelGGL(wtrans, gwt, blk, 0, stream, dense_w, dw_t);
    hipLaunchKernelGGL(gate_kernel, dim3(BL_ / 4), blk, 0, stream, query, gate_w, gate_b, gbuf);

    hipLaunchKernelGGL(gemmA<0>, gproj, blk, 0, stream, Qbf, mpq_t, mp_wq_b, (void*)R0);
    hipLaunchKernelGGL(gemmA<0>, gproj, blk, 0, stream, Kbf, mpk_t, mp_wk_b, (void*)R1);
    hipLaunchKernelGGL(mask16, gmask, blk, 0, stream, R0, R1, outm);
    hipLaunchKernelGGL(gemmA<0>, gproj, blk, 0, stream, Qbf, wq_t, wq_b, (void*)R0);
    hipLaunchKernelGGL(gemmA<0>, gproj, blk, 0, stream, Kbf, wk_t, wk_b, (void*)R1);
    hipLaunchKernelGGL(gemmA<1>, gproj, blk, 0, stream, Vbf, wv_t, wv_b, (void*)Vt);
    hipLaunchKernelGGL(attn2, gattn, blk, 0, stream, R0, R1, Vt, outm, gbuf, R0);
    hipLaunchKernelGGL(gemmA<2>, gproj, blk, 0, stream, R0, dw_t, dense_b, (void*)out0);
  } else {
    // -------- fallback (8 MB ws): round-6 GEMMs + attn v2 --------
    hipLaunchKernelGGL((gemm16<0, float>), gproj, blk, 0, stream, query, mp_wq_w, mp_wq_b, (void*)R0);
    hipLaunchKernelGGL((gemm16<0, float>), gproj, blk, 0, stream, key,   mp_wk_w, mp_wk_b, (void*)R1);
    hipLaunchKernelGGL(mask16, gmask, blk, 0, stream, R0, R1, outm);
    hipLaunchKernelGGL((gemm16<0, float>), gproj, blk, 0, stream, query, wq_w, wq_b, (void*)R0);
    hipLaunchKernelGGL((gemm16<0, float>), gproj, blk, 0, stream, key,   wk_w, wk_b, (void*)R1);
    hipLaunchKernelGGL((gemm16<1, float>), gproj, blk, 0, stream, value, wv_w, wv_b, (void*)Vt);
    hipLaunchKernelGGL(gate_kernel, dim3(BL_ / 4), blk, 0, stream, query, gate_w, gate_b, gbuf);
    hipLaunchKernelGGL(attn2, gattn, blk, 0, stream, R0, R1, Vt, outm, gbuf, R0);
    hipLaunchKernelGGL((gemm16<2, us16>), gproj, blk, 0, stream, R0, dense_w, dense_b, (void*)out0);
  }
}

// Round 8
// 273.523 us; speedup vs baseline: 1.4385x; 1.4385x over previous
//
#include <hip/hip_runtime.h>

#define B_  4
#define L_  1024
#define D_  512
#define H_  8
#define DK_ 64
#define BL_ (B_*L_)

typedef unsigned short us16;   // raw bf16 bits
typedef __attribute__((ext_vector_type(8))) short bf16x8;
typedef __attribute__((ext_vector_type(4))) float f32x4;

__device__ __forceinline__ float us2f(us16 u) {
  union { unsigned int i; float f; } x;
  x.i = ((unsigned int)u) << 16;
  return x.f;
}
__device__ __forceinline__ us16 f2us(float f) {
  union { float f; unsigned int i; } x;
  x.f = f;
  unsigned int r = x.i + 0x7FFFu + ((x.i >> 16) & 1u);  // RNE
  return (us16)(r >> 16);
}
__device__ __forceinline__ us16 cvt_us(float f) { return f2us(f); }
__device__ __forceinline__ us16 cvt_us(us16 u) { return u; }

#define MFMA(a, b, c) __builtin_amdgcn_mfma_f32_16x16x32_bf16(a, b, c, 0, 0, 0)

// ---------------------------------------------------------------------------
// Elementwise f32 -> bf16 (vectorized).
// ---------------------------------------------------------------------------
__global__ __launch_bounds__(256) void cvt_bf16(
    const float* __restrict__ src, us16* __restrict__ dst) {
  size_t i = ((size_t)blockIdx.x * 256 + threadIdx.x) * 4;
  float4 v = *(const float4*)(src + i);
  union { ushort4 v4; us16 u[4]; } o;
  o.u[0] = f2us(v.x); o.u[1] = f2us(v.y); o.u[2] = f2us(v.z); o.u[3] = f2us(v.w);
  *(ushort4*)(dst + i) = o.v4;
}

// ---------------------------------------------------------------------------
// Weight transpose+cvt: W f32 [512 k][512 n] -> Wt bf16 [n][k]. grid (8,8).
// ---------------------------------------------------------------------------
__global__ __launch_bounds__(256) void wtrans(
    const float* __restrict__ W, us16* __restrict__ Wt) {
  __shared__ us16 T[64][72];
  const int t = threadIdx.x;
  const int k0 = blockIdx.y * 64, n0 = blockIdx.x * 64;
  {
    int r = t >> 2, c = (t & 3) * 16;
    const float* src = W + (size_t)(k0 + r) * 512 + n0 + c;
    union { bf16x8 v; us16 u[8]; } p0, p1;
#pragma unroll
    for (int j = 0; j < 8; ++j) { p0.u[j] = f2us(src[j]); p1.u[j] = f2us(src[8 + j]); }
    *(bf16x8*)&T[r][c] = p0.v;
    *(bf16x8*)&T[r][c + 8] = p1.v;
  }
  __syncthreads();
  {
    int n = t >> 2, c = (t & 3) * 16;
    union { bf16x8 v; us16 u[8]; } p0, p1;
#pragma unroll
    for (int j = 0; j < 8; ++j) { p0.u[j] = T[c + j][n]; p1.u[j] = T[c + 8 + j][n]; }
    us16* dst = Wt + (size_t)(n0 + n) * 512 + k0 + c;
    *(bf16x8*)dst = p0.v;
    *(bf16x8*)(dst + 8) = p1.v;
  }
}

// ---------------------------------------------------------------------------
// Fast GEMM: C = A(bf16, Mx512) @ Wt(bf16 [n][k]) + bias(f32). BK=64.
// MODE 0: C bf16 [.][512]; 1: Vt [b][h][dk][kv]; 2: f32 row-major.
// ---------------------------------------------------------------------------
template <int MODE>
__global__ __launch_bounds__(256) void gemmA(
    const us16* __restrict__ A, const us16* __restrict__ Wt,
    const float* __restrict__ bias, void* __restrict__ Cout) {
  __shared__ us16 Al[64][72];
  __shared__ us16 Wl[64][72];
  const int tid = threadIdx.x;
  const int w = tid >> 6, lane = tid & 63;
  const int quad = lane >> 4, lc = lane & 15;
  const int row0 = blockIdx.y * 64, col0 = blockIdx.x * 64;
  const int sr = tid >> 2, sc = (tid & 3) * 16;
  f32x4 acc[4] = {};
  for (int k0 = 0; k0 < 512; k0 += 64) {
    const us16* as = A + (size_t)(row0 + sr) * 512 + k0 + sc;
    const us16* wsrc = Wt + (size_t)(col0 + sr) * 512 + k0 + sc;
    *(bf16x8*)&Al[sr][sc] = *(const bf16x8*)as;
    *(bf16x8*)&Al[sr][sc + 8] = *(const bf16x8*)(as + 8);
    *(bf16x8*)&Wl[sr][sc] = *(const bf16x8*)wsrc;
    *(bf16x8*)&Wl[sr][sc + 8] = *(const bf16x8*)(wsrc + 8);
    __syncthreads();
    bf16x8 a0 = *(const bf16x8*)&Al[w * 16 + lc][quad * 8];
    bf16x8 a1 = *(const bf16x8*)&Al[w * 16 + lc][32 + quad * 8];
#pragma unroll
    for (int ct = 0; ct < 4; ++ct) {
      bf16x8 b0 = *(const bf16x8*)&Wl[ct * 16 + lc][quad * 8];
      bf16x8 b1 = *(const bf16x8*)&Wl[ct * 16 + lc][32 + quad * 8];
      acc[ct] = MFMA(a0, b0, acc[ct]);
      acc[ct] = MFMA(a1, b1, acc[ct]);
    }
    __syncthreads();
  }
  const int orow = row0 + w * 16 + quad * 4;
#pragma unroll
  for (int ct = 0; ct < 4; ++ct) {
    const int col = col0 + ct * 16 + lc;
    const float bv = bias[col];
    if (MODE == 0) {
      us16* C = (us16*)Cout;
#pragma unroll
      for (int r = 0; r < 4; ++r)
        C[(size_t)(orow + r) * 512 + col] = f2us(acc[ct][r] + bv);
    } else if (MODE == 1) {
      us16* C = (us16*)Cout;
      const int h = col >> 6, dk = col & 63;
#pragma unroll
      for (int r = 0; r < 4; ++r) {
        const int grow = orow + r;
        const int b = grow >> 10, kv = grow & 1023;
        C[(((size_t)b * H_ + h) * DK_ + dk) * L_ + kv] = f2us(acc[ct][r] + bv);
      }
    } else {
      float* C = (float*)Cout;
#pragma unroll
      for (int r = 0; r < 4; ++r)
        C[(size_t)(orow + r) * 512 + col] = acc[ct][r] + bv;
    }
  }
}

// ---------------------------------------------------------------------------
// Fallback GEMM: A f32/us16, W f32 row-major, in-kernel transpose.
// ---------------------------------------------------------------------------
template <int MODE, typename TA>
__global__ __launch_bounds__(256) void gemm16(
    const TA* __restrict__ A, const float* __restrict__ W,
    const float* __restrict__ bias, void* __restrict__ Cout) {
  __shared__ us16 Al[64][56];
  __shared__ us16 Wl[64][56];
  const int tid = threadIdx.x;
  const int w = tid >> 6, lane = tid & 63;
  const int quad = lane >> 4, lc = lane & 15;
  const int row0 = blockIdx.y * 64, col0 = blockIdx.x * 64;
  f32x4 acc[4] = {};
  const int arow = tid >> 2, aks = (tid & 3) * 8;
  const int wk = tid & 31, wns = (tid >> 5) * 8;
  for (int k0 = 0; k0 < 512; k0 += 32) {
    {
      union { bf16x8 v; us16 u[8]; } pk;
      const TA* src = A + (size_t)(row0 + arow) * 512 + k0 + aks;
#pragma unroll
      for (int j = 0; j < 8; ++j) pk.u[j] = cvt_us(src[j]);
      *(bf16x8*)&Al[arow][aks] = pk.v;
    }
    {
      const float* src = W + (size_t)(k0 + wk) * 512 + col0 + wns;
#pragma unroll
      for (int j = 0; j < 8; ++j) Wl[wns + j][wk] = f2us(src[j]);
    }
    __syncthreads();
    bf16x8 af = *(const bf16x8*)&Al[w * 16 + lc][quad * 8];
#pragma unroll
    for (int ct = 0; ct < 4; ++ct) {
      bf16x8 bf = *(const bf16x8*)&Wl[ct * 16 + lc][quad * 8];
      acc[ct] = MFMA(af, bf, acc[ct]);
    }
    __syncthreads();
  }
  const int orow = row0 + w * 16 + quad * 4;
#pragma unroll
  for (int ct = 0; ct < 4; ++ct) {
    const int col = col0 + ct * 16 + lc;
    const float bv = bias[col];
    if (MODE == 0) {
      us16* C = (us16*)Cout;
#pragma unroll
      for (int r = 0; r < 4; ++r)
        C[(size_t)(orow + r) * 512 + col] = f2us(acc[ct][r] + bv);
    } else if (MODE == 1) {
      us16* C = (us16*)Cout;
      const int h = col >> 6, dk = col & 63;
#pragma unroll
      for (int r = 0; r < 4; ++r) {
        const int grow = orow + r;
        const int b = grow >> 10, kv = grow & 1023;
        C[(((size_t)b * H_ + h) * DK_ + dk) * L_ + kv] = f2us(acc[ct][r] + bv);
      }
    } else {
      float* C = (float*)Cout;
#pragma unroll
      for (int r = 0; r < 4; ++r)
        C[(size_t)(orow + r) * 512 + col] = acc[ct][r] + bv;
    }
  }
}

// ---------------------------------------------------------------------------
// Mask: m = sigmoid(QP.KP^T / sqrt(512)) -> f32. NT MFMA.
// ---------------------------------------------------------------------------
__global__ __launch_bounds__(256) void mask16(
    const us16* __restrict__ QP, const us16* __restrict__ KP,
    float* __restrict__ Mout) {
  __shared__ us16 Al[64][56];
  __shared__ us16 Bl[64][56];
  const int tid = threadIdx.x;
  const int w = tid >> 6, lane = tid & 63;
  const int quad = lane >> 4, lc = lane & 15;
  const int b = blockIdx.z;
  const int row0 = blockIdx.y * 64, col0 = blockIdx.x * 64;
  const us16* Ab = QP + (size_t)b * L_ * D_;
  const us16* Bb = KP + (size_t)b * L_ * D_;
  f32x4 acc[4] = {};
  const int arow = tid >> 2, aks = (tid & 3) * 8;
  for (int k0 = 0; k0 < 512; k0 += 32) {
    *(bf16x8*)&Al[arow][aks] =
        *(const bf16x8*)(Ab + (size_t)(row0 + arow) * 512 + k0 + aks);
    *(bf16x8*)&Bl[arow][aks] =
        *(const bf16x8*)(Bb + (size_t)(col0 + arow) * 512 + k0 + aks);
    __syncthreads();
    bf16x8 af = *(const bf16x8*)&Al[w * 16 + lc][quad * 8];
#pragma unroll
    for (int ct = 0; ct < 4; ++ct) {
      bf16x8 bf = *(const bf16x8*)&Bl[ct * 16 + lc][quad * 8];
      acc[ct] = MFMA(af, bf, acc[ct]);
    }
    __syncthreads();
  }
  const float sc = 0.04419417382415922f;  // 1/sqrt(512)
  const int orow = row0 + w * 16 + quad * 4;
#pragma unroll
  for (int ct = 0; ct < 4; ++ct) {
    const int col = col0 + ct * 16 + lc;
#pragma unroll
    for (int r = 0; r < 4; ++r) {
      float x = acc[ct][r] * sc;
      Mout[((size_t)b * L_ + orow + r) * L_ + col] = 1.f / (1.f + __expf(-x));
    }
  }
}

// g[row] = sigmoid(query[row,:] . gate_w + gate_b)
__global__ __launch_bounds__(256) void gate_kernel(
    const float* __restrict__ query, const float* __restrict__ gw,
    const float* __restrict__ gb, float* __restrict__ g) {
  int row = blockIdx.x * 4 + (threadIdx.x >> 6);
  int lane = threadIdx.x & 63;
  float p = 0.f;
  for (int d = lane; d < D_; d += 64) p += query[(size_t)row * D_ + d] * gw[d];
#pragma unroll
  for (int off = 32; off; off >>= 1) p += __shfl_down(p, off);
  if (lane == 0) g[row] = 1.f / (1.f + __expf(-(p + gb[0])));
}

// ---------------------------------------------------------------------------
// Attention v2b: scores in REGISTERS, FULLY unrolled (constant indices only —
// round 7's `unroll 4` caused dynamic indexing -> scratch spill -> 510 MB HBM
// writes). Double softmax via 4 cross-wave LDS reduction rounds; P bf16 in
// LDS; PV mfma with Vt [b][h][dk][kv]. O written in place over Qp.
// ---------------------------------------------------------------------------
__global__ __launch_bounds__(256, 3) void attn2(
    const us16* Qp, const us16* __restrict__ Kp,
    const us16* __restrict__ Vt, const float* __restrict__ Mm,
    const float* __restrict__ gbuf, us16* O) {
  __shared__ us16 Ql[16][72];
  __shared__ us16 P[16 * 1032];
  __shared__ float red[4][4][16];   // [round][wave][row]
  const int tid = threadIdx.x;
  const int w = tid >> 6, lane = tid & 63;
  const int quad = lane >> 4, lc = lane & 15;
  const int b = blockIdx.z, h = blockIdx.y, q0 = blockIdx.x * 16;

  if (tid < 128) {
    int r = tid >> 3, ks = (tid & 7) * 8;
    *(bf16x8*)&Ql[r][ks] =
        *(const bf16x8*)(Qp + (size_t)(b * L_ + q0 + r) * D_ + h * DK_ + ks);
  }
  __syncthreads();

  bf16x8 qa0 = *(const bf16x8*)&Ql[lc][quad * 8];
  bf16x8 qa1 = *(const bf16x8*)&Ql[lc][32 + quad * 8];

  // QK^T: thread holds s[kt][r] = S[row=quad*4+r][col=kt*64+w*16+lc]
  const us16* Kbase = Kp + (size_t)b * L_ * D_ + h * DK_;
  float s[16][4];
#pragma unroll
  for (int kt = 0; kt < 16; ++kt) {
    const us16* kr = Kbase + (size_t)(kt * 64 + w * 16 + lc) * D_;
    bf16x8 b0 = *(const bf16x8*)(kr + quad * 8);
    bf16x8 b1 = *(const bf16x8*)(kr + 32 + quad * 8);
    f32x4 a = {};
    a = MFMA(qa0, b0, a);
    a = MFMA(qa1, b1, a);
#pragma unroll
    for (int r = 0; r < 4; ++r) s[kt][r] = a[r] * 0.125f;  // 1/sqrt(64)
  }

  // ---- round 0: first max
  float mx[4];
#pragma unroll
  for (int r = 0; r < 4; ++r) {
    float m = s[0][r];
#pragma unroll
    for (int kt = 1; kt < 16; ++kt) m = fmaxf(m, s[kt][r]);
#pragma unroll
    for (int off = 1; off < 16; off <<= 1) m = fmaxf(m, __shfl_xor(m, off));
    mx[r] = m;
  }
  if (lc == 0)
#pragma unroll
    for (int r = 0; r < 4; ++r) red[0][w][quad * 4 + r] = mx[r];
  __syncthreads();
#pragma unroll
  for (int r = 0; r < 4; ++r) {
    const int row = quad * 4 + r;
    mx[r] = fmaxf(fmaxf(red[0][0][row], red[0][1][row]),
                  fmaxf(red[0][2][row], red[0][3][row]));
  }

  // ---- round 1: exp + first sum
  float sm[4];
#pragma unroll
  for (int r = 0; r < 4; ++r) {
    float t = 0.f;
#pragma unroll
    for (int kt = 0; kt < 16; ++kt) { s[kt][r] = __expf(s[kt][r] - mx[r]); t += s[kt][r]; }
#pragma unroll
    for (int off = 1; off < 16; off <<= 1) t += __shfl_xor(t, off);
    sm[r] = t;
  }
  if (lc == 0)
#pragma unroll
    for (int r = 0; r < 4; ++r) red[1][w][quad * 4 + r] = sm[r];
  __syncthreads();
  float inv[4];
#pragma unroll
  for (int r = 0; r < 4; ++r) {
    const int row = quad * 4 + r;
    inv[r] = 1.f / (red[1][0][row] + red[1][1][row] + red[1][2][row] + red[1][3][row]);
  }

  // ---- calibration: c = p * (g + (1-g)*exp(1-m)), then round 2: second max
  float gq[4];
#pragma unroll
  for (int r = 0; r < 4; ++r) gq[r] = gbuf[b * L_ + q0 + quad * 4 + r];
#pragma unroll
  for (int r = 0; r < 4; ++r) {
    const float* mrow = Mm + (size_t)(b * L_ + q0 + quad * 4 + r) * L_;
    float m2 = -1e30f;
#pragma unroll
    for (int kt = 0; kt < 16; ++kt) {
      float mval = mrow[kt * 64 + w * 16 + lc];
      float c = s[kt][r] * inv[r] * (gq[r] + (1.f - gq[r]) * __expf(1.f - mval));
      s[kt][r] = c;
      m2 = fmaxf(m2, c);
    }
#pragma unroll
    for (int off = 1; off < 16; off <<= 1) m2 = fmaxf(m2, __shfl_xor(m2, off));
    mx[r] = m2;
  }
  if (lc == 0)
#pragma unroll
    for (int r = 0; r < 4; ++r) red[2][w][quad * 4 + r] = mx[r];
  __syncthreads();
#pragma unroll
  for (int r = 0; r < 4; ++r) {
    const int row = quad * 4 + r;
    mx[r] = fmaxf(fmaxf(red[2][0][row], red[2][1][row]),
                  fmaxf(red[2][2][row], red[2][3][row]));
  }

  // ---- round 3: second exp + sum
#pragma unroll
  for (int r = 0; r < 4; ++r) {
    float t = 0.f;
#pragma unroll
    for (int kt = 0; kt < 16; ++kt) { s[kt][r] = __expf(s[kt][r] - mx[r]); t += s[kt][r]; }
#pragma unroll
    for (int off = 1; off < 16; off <<= 1) t += __shfl_xor(t, off);
    sm[r] = t;
  }
  if (lc == 0)
#pragma unroll
    for (int r = 0; r < 4; ++r) red[3][w][quad * 4 + r] = sm[r];
  __syncthreads();
#pragma unroll
  for (int r = 0; r < 4; ++r) {
    const int row = quad * 4 + r;
    inv[r] = 1.f / (red[3][0][row] + red[3][1][row] + red[3][2][row] + red[3][3][row]);
  }

  // ---- P (bf16) to LDS, A-operand layout [row][kv], stride 1032
#pragma unroll
  for (int kt = 0; kt < 16; ++kt)
#pragma unroll
    for (int r = 0; r < 4; ++r)
      P[(quad * 4 + r) * 1032 + kt * 64 + w * 16 + lc] = f2us(s[kt][r] * inv[r]);
  __syncthreads();

  // ---- PV: wave w computes dk slice w*16+lc
  const us16* Vb = Vt + (size_t)(b * H_ + h) * DK_ * L_;  // [dk][kv]
  f32x4 oacc = {};
  for (int kv = 0; kv < L_; kv += 32) {
    bf16x8 pa = *(const bf16x8*)&P[lc * 1032 + kv + quad * 8];
    bf16x8 vb = *(const bf16x8*)(Vb + (size_t)(w * 16 + lc) * L_ + kv + quad * 8);
    oacc = MFMA(pa, vb, oacc);
  }
#pragma unroll
  for (int r = 0; r < 4; ++r)
    O[(size_t)(b * L_ + q0 + quad * 4 + r) * D_ + h * DK_ + w * 16 + lc] =
        f2us(oacc[r]);
}

extern "C" void kernel_launch(void* const* d_in, const int* in_sizes, int n_in,
                              void* d_out, int out_size, void* d_ws, size_t ws_size,
                              hipStream_t stream) {
  const float* query   = (const float*)d_in[0];
  const float* key     = (const float*)d_in[1];
  const float* value   = (const float*)d_in[2];
  const float* wq_w    = (const float*)d_in[3];
  const float* wq_b    = (const float*)d_in[4];
  const float* wk_w    = (const float*)d_in[5];
  const float* wk_b    = (const float*)d_in[6];
  const float* wv_w    = (const float*)d_in[7];
  const float* wv_b    = (const float*)d_in[8];
  const float* dense_w = (const float*)d_in[9];
  const float* dense_b = (const float*)d_in[10];
  const float* gate_w  = (const float*)d_in[11];
  const float* gate_b  = (const float*)d_in[12];
  const float* mp_wq_w = (const float*)d_in[13];
  const float* mp_wq_b = (const float*)d_in[14];
  const float* mp_wk_w = (const float*)d_in[15];
  const float* mp_wk_b = (const float*)d_in[16];

  const size_t RSZ = (size_t)BL_ * D_;   // 2,097,152 elems
  const size_t WSZ = (size_t)D_ * D_;    // 262,144 elems
  us16* R0 = (us16*)d_ws;
  us16* R1 = R0 + RSZ;

  float* out0 = (float*)d_out;                 // final out f32 (8 MB)
  float* outm = out0 + (size_t)B_ * L_ * D_;   // m f32 (16 MB)
  us16*  Vt   = (us16*)d_out;                  // V^T bf16 in out bytes [0,4M)
  float* gbuf = (float*)((char*)d_out + (4u << 20));

  dim3 blk(256);
  dim3 gproj(8, 64);
  dim3 gmask(16, 16, B_);
  dim3 gattn(L_ / 16, H_, B_);

  if (ws_size >= ((size_t)24 << 20)) {
    // -------- big-ws path: pre-cvt inputs + pre-transposed weights --------
    us16* Wt0 = R1 + RSZ;            // 6 x 512KB at ws+8M
    us16* mpq_t = Wt0;
    us16* mpk_t = Wt0 + WSZ;
    us16* wq_t  = Wt0 + 2 * WSZ;
    us16* wk_t  = Wt0 + 3 * WSZ;
    us16* wv_t  = Wt0 + 4 * WSZ;
    us16* dw_t  = Wt0 + 5 * WSZ;
    us16* Qbf = Wt0 + 6 * WSZ;       // ws+11M
    us16* Kbf = Qbf + RSZ;           // ws+15M
    us16* Vbf = Kbf + RSZ;           // ws+19M .. 23M

    dim3 gcvt(RSZ / (256 * 4));
    dim3 gwt(8, 8);
    hipLaunchKernelGGL(cvt_bf16, gcvt, blk, 0, stream, query, Qbf);
    hipLaunchKernelGGL(cvt_bf16, gcvt, blk, 0, stream, key,   Kbf);
    hipLaunchKernelGGL(cvt_bf16, gcvt, blk, 0, stream, value, Vbf);
    hipLaunchKernelGGL(wtrans, gwt, blk, 0, stream, mp_wq_w, mpq_t);
    hipLaunchKernelGGL(wtrans, gwt, blk, 0, stream, mp_wk_w, mpk_t);
    hipLaunchKernelGGL(wtrans, gwt, blk, 0, stream, wq_w, wq_t);
    hipLaunchKernelGGL(wtrans, gwt, blk, 0, stream, wk_w, wk_t);
    hipLaunchKernelGGL(wtrans, gwt, blk, 0, stream, wv_w, wv_t);
    hipLaunchKernelGGL(wtrans, gwt, blk, 0, stream, dense_w, dw_t);
    hipLaunchKernelGGL(gate_kernel, dim3(BL_ / 4), blk, 0, stream, query, gate_w, gate_b, gbuf);

    hipLaunchKernelGGL(gemmA<0>, gproj, blk, 0, stream, Qbf, mpq_t, mp_wq_b, (void*)R0);
    hipLaunchKernelGGL(gemmA<0>, gproj, blk, 0, stream, Kbf, mpk_t, mp_wk_b, (void*)R1);
    hipLaunchKernelGGL(mask16, gmask, blk, 0, stream, R0, R1, outm);
    hipLaunchKernelGGL(gemmA<0>, gproj, blk, 0, stream, Qbf, wq_t, wq_b, (void*)R0);
    hipLaunchKernelGGL(gemmA<0>, gproj, blk, 0, stream, Kbf, wk_t, wk_b, (void*)R1);
    hipLaunchKernelGGL(gemmA<1>, gproj, blk, 0, stream, Vbf, wv_t, wv_b, (void*)Vt);
    hipLaunchKernelGGL(attn2, gattn, blk, 0, stream, R0, R1, Vt, outm, gbuf, R0);
    hipLaunchKernelGGL(gemmA<2>, gproj, blk, 0, stream, R0, dw_t, dense_b, (void*)out0);
  } else {
    // -------- fallback (8 MB ws) --------
    hipLaunchKernelGGL((gemm16<0, float>), gproj, blk, 0, stream, query, mp_wq_w, mp_wq_b, (void*)R0);
    hipLaunchKernelGGL((gemm16<0, float>), gproj, blk, 0, stream, key,   mp_wk_w, mp_wk_b, (void*)R1);
    hipLaunchKernelGGL(mask16, gmask, blk, 0, stream, R0, R1, outm);
    hipLaunchKernelGGL((gemm16<0, float>), gproj, blk, 0, stream, query, wq_w, wq_b, (void*)R0);
    hipLaunchKernelGGL((gemm16<0, float>), gproj, blk, 0, stream, key,   wk_w, wk_b, (void*)R1);
    hipLaunchKernelGGL((gemm16<1, float>), gproj, blk, 0, stream, value, wv_w, wv_b, (void*)Vt);
    hipLaunchKernelGGL(gate_kernel, dim3(BL_ / 4), blk, 0, stream, query, gate_w, gate_b, gbuf);
    hipLaunchKernelGGL(attn2, gattn, blk, 0, stream, R0, R1, Vt, outm, gbuf, R0);
    hipLaunchKernelGGL((gemm16<2, us16>), gproj, blk, 0, stream, R0, dense_w, dense_b, (void*)out0);
  }
}

// Round 9
// 261.436 us; speedup vs baseline: 1.5050x; 1.0462x over previous
//
#include <hip/hip_runtime.h>

#define B_  4
#define L_  1024
#define D_  512
#define H_  8
#define DK_ 64
#define BL_ (B_*L_)

typedef unsigned short us16;   // raw bf16 bits
typedef __attribute__((ext_vector_type(8))) short bf16x8;
typedef __attribute__((ext_vector_type(4))) float f32x4;

__device__ __forceinline__ float us2f(us16 u) {
  union { unsigned int i; float f; } x;
  x.i = ((unsigned int)u) << 16;
  return x.f;
}
__device__ __forceinline__ us16 f2us(float f) {
  union { float f; unsigned int i; } x;
  x.f = f;
  unsigned int r = x.i + 0x7FFFu + ((x.i >> 16) & 1u);  // RNE
  return (us16)(r >> 16);
}
__device__ __forceinline__ us16 cvt_us(float f) { return f2us(f); }
__device__ __forceinline__ us16 cvt_us(us16 u) { return u; }

#define MFMA(a, b, c) __builtin_amdgcn_mfma_f32_16x16x32_bf16(a, b, c, 0, 0, 0)

// ---------------------------------------------------------------------------
// Fused weight transpose+cvt: 6 matrices, W f32 [k][n] -> bf16 [n][k].
// grid (8, 8, 6).
// ---------------------------------------------------------------------------
struct WT6 {
  const float* src[6];
  us16* dst[6];
};
__global__ __launch_bounds__(256) void wtrans6(WT6 p) {
  __shared__ us16 T[64][72];
  const int z = blockIdx.z;
  const float* __restrict__ W = p.src[z];
  us16* __restrict__ Wt = p.dst[z];
  const int t = threadIdx.x;
  const int k0 = blockIdx.y * 64, n0 = blockIdx.x * 64;
  {
    int r = t >> 2, c = (t & 3) * 16;
    const float* src = W + (size_t)(k0 + r) * 512 + n0 + c;
    union { bf16x8 v; us16 u[8]; } p0, p1;
#pragma unroll
    for (int j = 0; j < 8; ++j) { p0.u[j] = f2us(src[j]); p1.u[j] = f2us(src[8 + j]); }
    *(bf16x8*)&T[r][c] = p0.v;
    *(bf16x8*)&T[r][c + 8] = p1.v;
  }
  __syncthreads();
  {
    int n = t >> 2, c = (t & 3) * 16;
    union { bf16x8 v; us16 u[8]; } p0, p1;
#pragma unroll
    for (int j = 0; j < 8; ++j) { p0.u[j] = T[c + j][n]; p1.u[j] = T[c + 8 + j][n]; }
    us16* dst = Wt + (size_t)(n0 + n) * 512 + k0 + c;
    *(bf16x8*)dst = p0.v;
    *(bf16x8*)(dst + 8) = p1.v;
  }
}

// ---------------------------------------------------------------------------
// Batched projection GEMM: per-z job. C = A(f32, 4096x512) @ Wt(bf16 [n][k])
// + bias. mode 0: C bf16 row-major; mode 1: C bf16 Vt [b][h][dk][kv].
// ---------------------------------------------------------------------------
struct GJob { const float* A; const us16* Wt; const float* bias; us16* C; int mode; };
struct GJobs { GJob j[3]; };

__global__ __launch_bounds__(256) void gemm3(GJobs jobs) {
  __shared__ us16 Al[64][72];
  __shared__ us16 Wl[64][72];
  const GJob J = jobs.j[blockIdx.z];
  const int tid = threadIdx.x;
  const int w = tid >> 6, lane = tid & 63;
  const int quad = lane >> 4, lc = lane & 15;
  const int row0 = blockIdx.y * 64, col0 = blockIdx.x * 64;
  const int sr = tid >> 2, sc = (tid & 3) * 16;
  f32x4 acc[4] = {};
  for (int k0 = 0; k0 < 512; k0 += 64) {
    {
      const float* as = J.A + (size_t)(row0 + sr) * 512 + k0 + sc;
      union { bf16x8 v; us16 u[8]; } p0, p1;
#pragma unroll
      for (int j = 0; j < 8; ++j) { p0.u[j] = f2us(as[j]); p1.u[j] = f2us(as[8 + j]); }
      *(bf16x8*)&Al[sr][sc] = p0.v;
      *(bf16x8*)&Al[sr][sc + 8] = p1.v;
    }
    {
      const us16* wsrc = J.Wt + (size_t)(col0 + sr) * 512 + k0 + sc;
      *(bf16x8*)&Wl[sr][sc] = *(const bf16x8*)wsrc;
      *(bf16x8*)&Wl[sr][sc + 8] = *(const bf16x8*)(wsrc + 8);
    }
    __syncthreads();
    bf16x8 a0 = *(const bf16x8*)&Al[w * 16 + lc][quad * 8];
    bf16x8 a1 = *(const bf16x8*)&Al[w * 16 + lc][32 + quad * 8];
#pragma unroll
    for (int ct = 0; ct < 4; ++ct) {
      bf16x8 b0 = *(const bf16x8*)&Wl[ct * 16 + lc][quad * 8];
      bf16x8 b1 = *(const bf16x8*)&Wl[ct * 16 + lc][32 + quad * 8];
      acc[ct] = MFMA(a0, b0, acc[ct]);
      acc[ct] = MFMA(a1, b1, acc[ct]);
    }
    __syncthreads();
  }
  const int orow = row0 + w * 16 + quad * 4;
#pragma unroll
  for (int ct = 0; ct < 4; ++ct) {
    const int col = col0 + ct * 16 + lc;
    const float bv = J.bias[col];
    if (J.mode == 0) {
#pragma unroll
      for (int r = 0; r < 4; ++r)
        J.C[(size_t)(orow + r) * 512 + col] = f2us(acc[ct][r] + bv);
    } else {
      const int h = col >> 6, dk = col & 63;
#pragma unroll
      for (int r = 0; r < 4; ++r) {
        const int grow = orow + r;
        const int b = grow >> 10, kv = grow & 1023;
        J.C[(((size_t)b * H_ + h) * DK_ + dk) * L_ + kv] = f2us(acc[ct][r] + bv);
      }
    }
  }
}

// ---------------------------------------------------------------------------
// Dense: C(f32) = A(bf16 ws) @ Wt(bf16 [n][k]) + bias.
// ---------------------------------------------------------------------------
__global__ __launch_bounds__(256) void gemm_dense(
    const us16* __restrict__ A, const us16* __restrict__ Wt,
    const float* __restrict__ bias, float* __restrict__ C) {
  __shared__ us16 Al[64][72];
  __shared__ us16 Wl[64][72];
  const int tid = threadIdx.x;
  const int w = tid >> 6, lane = tid & 63;
  const int quad = lane >> 4, lc = lane & 15;
  const int row0 = blockIdx.y * 64, col0 = blockIdx.x * 64;
  const int sr = tid >> 2, sc = (tid & 3) * 16;
  f32x4 acc[4] = {};
  for (int k0 = 0; k0 < 512; k0 += 64) {
    const us16* as = A + (size_t)(row0 + sr) * 512 + k0 + sc;
    const us16* wsrc = Wt + (size_t)(col0 + sr) * 512 + k0 + sc;
    *(bf16x8*)&Al[sr][sc] = *(const bf16x8*)as;
    *(bf16x8*)&Al[sr][sc + 8] = *(const bf16x8*)(as + 8);
    *(bf16x8*)&Wl[sr][sc] = *(const bf16x8*)wsrc;
    *(bf16x8*)&Wl[sr][sc + 8] = *(const bf16x8*)(wsrc + 8);
    __syncthreads();
    bf16x8 a0 = *(const bf16x8*)&Al[w * 16 + lc][quad * 8];
    bf16x8 a1 = *(const bf16x8*)&Al[w * 16 + lc][32 + quad * 8];
#pragma unroll
    for (int ct = 0; ct < 4; ++ct) {
      bf16x8 b0 = *(const bf16x8*)&Wl[ct * 16 + lc][quad * 8];
      bf16x8 b1 = *(const bf16x8*)&Wl[ct * 16 + lc][32 + quad * 8];
      acc[ct] = MFMA(a0, b0, acc[ct]);
      acc[ct] = MFMA(a1, b1, acc[ct]);
    }
    __syncthreads();
  }
  const int orow = row0 + w * 16 + quad * 4;
#pragma unroll
  for (int ct = 0; ct < 4; ++ct) {
    const int col = col0 + ct * 16 + lc;
    const float bv = bias[col];
#pragma unroll
    for (int r = 0; r < 4; ++r)
      C[(size_t)(orow + r) * 512 + col] = acc[ct][r] + bv;
  }
}

// g[row] = sigmoid(query[row,:] . gate_w + gate_b)
__global__ __launch_bounds__(256) void gate_kernel(
    const float* __restrict__ query, const float* __restrict__ gw,
    const float* __restrict__ gb, float* __restrict__ g) {
  int row = blockIdx.x * 4 + (threadIdx.x >> 6);
  int lane = threadIdx.x & 63;
  float p = 0.f;
  for (int d = lane; d < D_; d += 64) p += query[(size_t)row * D_ + d] * gw[d];
#pragma unroll
  for (int off = 32; off; off >>= 1) p += __shfl_down(p, off);
  if (lane == 0) g[row] = 1.f / (1.f + __expf(-(p + gb[0])));
}

// ---------------------------------------------------------------------------
// Mask: m = sigmoid(QP.KP^T / sqrt(512)) -> f32 out.
// WK variant also writes wk = g + (1-g)*exp(1-m) as bf16 (head-independent
// calibration weight, reused 8x by attention).
// ---------------------------------------------------------------------------
template <bool WK>
__global__ __launch_bounds__(256) void mask16(
    const us16* __restrict__ QP, const us16* __restrict__ KP,
    float* __restrict__ Mout, const float* __restrict__ gbuf,
    us16* __restrict__ Wk) {
  __shared__ us16 Al[64][56];
  __shared__ us16 Bl[64][56];
  const int tid = threadIdx.x;
  const int w = tid >> 6, lane = tid & 63;
  const int quad = lane >> 4, lc = lane & 15;
  const int b = blockIdx.z;
  const int row0 = blockIdx.y * 64, col0 = blockIdx.x * 64;
  const us16* Ab = QP + (size_t)b * L_ * D_;
  const us16* Bb = KP + (size_t)b * L_ * D_;
  f32x4 acc[4] = {};
  const int arow = tid >> 2, aks = (tid & 3) * 8;
  for (int k0 = 0; k0 < 512; k0 += 32) {
    *(bf16x8*)&Al[arow][aks] =
        *(const bf16x8*)(Ab + (size_t)(row0 + arow) * 512 + k0 + aks);
    *(bf16x8*)&Bl[arow][aks] =
        *(const bf16x8*)(Bb + (size_t)(col0 + arow) * 512 + k0 + aks);
    __syncthreads();
    bf16x8 af = *(const bf16x8*)&Al[w * 16 + lc][quad * 8];
#pragma unroll
    for (int ct = 0; ct < 4; ++ct) {
      bf16x8 bf = *(const bf16x8*)&Bl[ct * 16 + lc][quad * 8];
      acc[ct] = MFMA(af, bf, acc[ct]);
    }
    __syncthreads();
  }
  const float sc = 0.04419417382415922f;  // 1/sqrt(512)
  const int orow = row0 + w * 16 + quad * 4;
  float gq[4];
  if (WK) {
#pragma unroll
    for (int r = 0; r < 4; ++r) gq[r] = gbuf[b * L_ + orow + r];
  }
#pragma unroll
  for (int ct = 0; ct < 4; ++ct) {
    const int col = col0 + ct * 16 + lc;
#pragma unroll
    for (int r = 0; r < 4; ++r) {
      float x = acc[ct][r] * sc;
      float v = 1.f / (1.f + __expf(-x));
      size_t idx = ((size_t)b * L_ + orow + r) * L_ + col;
      Mout[idx] = v;
      if (WK) Wk[idx] = f2us(gq[r] + (1.f - gq[r]) * __expf(1.f - v));
    }
  }
}

// ---------------------------------------------------------------------------
// Attention v3: scores in registers (fully unrolled); NO max subtraction
// (logits sigma~0.2 and comb <= e, exp args bounded, softmax shift-exact);
// calibration weight wk precomputed bf16; 2 cross-wave reductions, 4 barriers.
// O in place over Qp (blocks only touch their own cells).
// ---------------------------------------------------------------------------
__global__ __launch_bounds__(256, 4) void attn3(
    const us16* Qp, const us16* __restrict__ Kp,
    const us16* __restrict__ Vt, const us16* __restrict__ Wk, us16* O) {
  __shared__ us16 Ql[16][72];
  __shared__ us16 P[16 * 1032];
  __shared__ float red[2][4][16];
  const int tid = threadIdx.x;
  const int w = tid >> 6, lane = tid & 63;
  const int quad = lane >> 4, lc = lane & 15;
  const int b = blockIdx.z, h = blockIdx.y, q0 = blockIdx.x * 16;

  if (tid < 128) {
    int r = tid >> 3, ks = (tid & 7) * 8;
    *(bf16x8*)&Ql[r][ks] =
        *(const bf16x8*)(Qp + (size_t)(b * L_ + q0 + r) * D_ + h * DK_ + ks);
  }
  __syncthreads();

  bf16x8 qa0 = *(const bf16x8*)&Ql[lc][quad * 8];
  bf16x8 qa1 = *(const bf16x8*)&Ql[lc][32 + quad * 8];

  // QK^T: s[kt][r] = S[row=quad*4+r][col=kt*64+w*16+lc] / 8
  const us16* Kbase = Kp + (size_t)b * L_ * D_ + h * DK_;
  float s[16][4];
#pragma unroll
  for (int kt = 0; kt < 16; ++kt) {
    const us16* kr = Kbase + (size_t)(kt * 64 + w * 16 + lc) * D_;
    bf16x8 b0 = *(const bf16x8*)(kr + quad * 8);
    bf16x8 b1 = *(const bf16x8*)(kr + 32 + quad * 8);
    f32x4 a = {};
    a = MFMA(qa0, b0, a);
    a = MFMA(qa1, b1, a);
#pragma unroll
    for (int r = 0; r < 4; ++r) s[kt][r] = a[r] * 0.125f;
  }

  // ---- first softmax: exp + sum (no max: |s| <~ 2)
  float sm[4];
#pragma unroll
  for (int r = 0; r < 4; ++r) {
    float t = 0.f;
#pragma unroll
    for (int kt = 0; kt < 16; ++kt) { s[kt][r] = __expf(s[kt][r]); t += s[kt][r]; }
#pragma unroll
    for (int off = 1; off < 16; off <<= 1) t += __shfl_xor(t, off);
    sm[r] = t;
  }
  if (lc == 0)
#pragma unroll
    for (int r = 0; r < 4; ++r) red[0][w][quad * 4 + r] = sm[r];
  __syncthreads();
  float inv[4];
#pragma unroll
  for (int r = 0; r < 4; ++r) {
    const int row = quad * 4 + r;
    inv[r] = 1.f / (red[0][0][row] + red[0][1][row] + red[0][2][row] + red[0][3][row]);
  }

  // ---- calibrate (wk precomputed) + second exp + sum (comb <= e)
#pragma unroll
  for (int r = 0; r < 4; ++r) {
    const us16* wkr =
        Wk + (size_t)(b * L_ + q0 + quad * 4 + r) * L_ + w * 16 + lc;
    float t = 0.f;
#pragma unroll
    for (int kt = 0; kt < 16; ++kt) {
      float c = s[kt][r] * inv[r] * us2f(wkr[kt * 64]);
      float e = __expf(c);
      s[kt][r] = e;
      t += e;
    }
#pragma unroll
    for (int off = 1; off < 16; off <<= 1) t += __shfl_xor(t, off);
    sm[r] = t;
  }
  if (lc == 0)
#pragma unroll
    for (int r = 0; r < 4; ++r) red[1][w][quad * 4 + r] = sm[r];
  __syncthreads();
#pragma unroll
  for (int r = 0; r < 4; ++r) {
    const int row = quad * 4 + r;
    inv[r] = 1.f / (red[1][0][row] + red[1][1][row] + red[1][2][row] + red[1][3][row]);
  }

  // ---- P (bf16) to LDS, A-operand layout [row][kv]
#pragma unroll
  for (int kt = 0; kt < 16; ++kt)
#pragma unroll
    for (int r = 0; r < 4; ++r)
      P[(quad * 4 + r) * 1032 + kt * 64 + w * 16 + lc] = f2us(s[kt][r] * inv[r]);
  __syncthreads();

  // ---- PV: wave w computes dk slice w*16+lc
  const us16* Vb = Vt + (size_t)(b * H_ + h) * DK_ * L_;  // [dk][kv]
  f32x4 oacc = {};
  for (int kv = 0; kv < L_; kv += 32) {
    bf16x8 pa = *(const bf16x8*)&P[lc * 1032 + kv + quad * 8];
    bf16x8 vb = *(const bf16x8*)(Vb + (size_t)(w * 16 + lc) * L_ + kv + quad * 8);
    oacc = MFMA(pa, vb, oacc);
  }
#pragma unroll
  for (int r = 0; r < 4; ++r)
    O[(size_t)(b * L_ + q0 + quad * 4 + r) * D_ + h * DK_ + w * 16 + lc] =
        f2us(oacc[r]);
}

// ---------------------------------------------------------------------------
// Fallback kernels (small ws): round-8 path.
// ---------------------------------------------------------------------------
template <int MODE, typename TA>
__global__ __launch_bounds__(256) void gemm16(
    const TA* __restrict__ A, const float* __restrict__ W,
    const float* __restrict__ bias, void* __restrict__ Cout) {
  __shared__ us16 Al[64][56];
  __shared__ us16 Wl[64][56];
  const int tid = threadIdx.x;
  const int w = tid >> 6, lane = tid & 63;
  const int quad = lane >> 4, lc = lane & 15;
  const int row0 = blockIdx.y * 64, col0 = blockIdx.x * 64;
  f32x4 acc[4] = {};
  const int arow = tid >> 2, aks = (tid & 3) * 8;
  const int wk = tid & 31, wns = (tid >> 5) * 8;
  for (int k0 = 0; k0 < 512; k0 += 32) {
    {
      union { bf16x8 v; us16 u[8]; } pk;
      const TA* src = A + (size_t)(row0 + arow) * 512 + k0 + aks;
#pragma unroll
      for (int j = 0; j < 8; ++j) pk.u[j] = cvt_us(src[j]);
      *(bf16x8*)&Al[arow][aks] = pk.v;
    }
    {
      const float* src = W + (size_t)(k0 + wk) * 512 + col0 + wns;
#pragma unroll
      for (int j = 0; j < 8; ++j) Wl[wns + j][wk] = f2us(src[j]);
    }
    __syncthreads();
    bf16x8 af = *(const bf16x8*)&Al[w * 16 + lc][quad * 8];
#pragma unroll
    for (int ct = 0; ct < 4; ++ct) {
      bf16x8 bf = *(const bf16x8*)&Wl[ct * 16 + lc][quad * 8];
      acc[ct] = MFMA(af, bf, acc[ct]);
    }
    __syncthreads();
  }
  const int orow = row0 + w * 16 + quad * 4;
#pragma unroll
  for (int ct = 0; ct < 4; ++ct) {
    const int col = col0 + ct * 16 + lc;
    const float bv = bias[col];
    if (MODE == 0) {
      us16* C = (us16*)Cout;
#pragma unroll
      for (int r = 0; r < 4; ++r)
        C[(size_t)(orow + r) * 512 + col] = f2us(acc[ct][r] + bv);
    } else if (MODE == 1) {
      us16* C = (us16*)Cout;
      const int h = col >> 6, dk = col & 63;
#pragma unroll
      for (int r = 0; r < 4; ++r) {
        const int grow = orow + r;
        const int b = grow >> 10, kv = grow & 1023;
        C[(((size_t)b * H_ + h) * DK_ + dk) * L_ + kv] = f2us(acc[ct][r] + bv);
      }
    } else {
      float* C = (float*)Cout;
#pragma unroll
      for (int r = 0; r < 4; ++r)
        C[(size_t)(orow + r) * 512 + col] = acc[ct][r] + bv;
    }
  }
}

__global__ __launch_bounds__(256, 3) void attn2_fb(
    const us16* Qp, const us16* __restrict__ Kp,
    const us16* __restrict__ Vt, const float* __restrict__ Mm,
    const float* __restrict__ gbuf, us16* O) {
  __shared__ us16 Ql[16][72];
  __shared__ us16 P[16 * 1032];
  __shared__ float red[2][4][16];
  const int tid = threadIdx.x;
  const int w = tid >> 6, lane = tid & 63;
  const int quad = lane >> 4, lc = lane & 15;
  const int b = blockIdx.z, h = blockIdx.y, q0 = blockIdx.x * 16;
  if (tid < 128) {
    int r = tid >> 3, ks = (tid & 7) * 8;
    *(bf16x8*)&Ql[r][ks] =
        *(const bf16x8*)(Qp + (size_t)(b * L_ + q0 + r) * D_ + h * DK_ + ks);
  }
  __syncthreads();
  bf16x8 qa0 = *(const bf16x8*)&Ql[lc][quad * 8];
  bf16x8 qa1 = *(const bf16x8*)&Ql[lc][32 + quad * 8];
  const us16* Kbase = Kp + (size_t)b * L_ * D_ + h * DK_;
  float s[16][4];
#pragma unroll
  for (int kt = 0; kt < 16; ++kt) {
    const us16* kr = Kbase + (size_t)(kt * 64 + w * 16 + lc) * D_;
    bf16x8 b0 = *(const bf16x8*)(kr + quad * 8);
    bf16x8 b1 = *(const bf16x8*)(kr + 32 + quad * 8);
    f32x4 a = {};
    a = MFMA(qa0, b0, a);
    a = MFMA(qa1, b1, a);
#pragma unroll
    for (int r = 0; r < 4; ++r) s[kt][r] = a[r] * 0.125f;
  }
  float sm[4];
#pragma unroll
  for (int r = 0; r < 4; ++r) {
    float t = 0.f;
#pragma unroll
    for (int kt = 0; kt < 16; ++kt) { s[kt][r] = __expf(s[kt][r]); t += s[kt][r]; }
#pragma unroll
    for (int off = 1; off < 16; off <<= 1) t += __shfl_xor(t, off);
    sm[r] = t;
  }
  if (lc == 0)
#pragma unroll
    for (int r = 0; r < 4; ++r) red[0][w][quad * 4 + r] = sm[r];
  __syncthreads();
  float inv[4];
#pragma unroll
  for (int r = 0; r < 4; ++r) {
    const int row = quad * 4 + r;
    inv[r] = 1.f / (red[0][0][row] + red[0][1][row] + red[0][2][row] + red[0][3][row]);
  }
  float gq[4];
#pragma unroll
  for (int r = 0; r < 4; ++r) gq[r] = gbuf[b * L_ + q0 + quad * 4 + r];
#pragma unroll
  for (int r = 0; r < 4; ++r) {
    const float* mrow = Mm + (size_t)(b * L_ + q0 + quad * 4 + r) * L_;
    float t = 0.f;
#pragma unroll
    for (int kt = 0; kt < 16; ++kt) {
      float mval = mrow[kt * 64 + w * 16 + lc];
      float c = s[kt][r] * inv[r] * (gq[r] + (1.f - gq[r]) * __expf(1.f - mval));
      float e = __expf(c);
      s[kt][r] = e;
      t += e;
    }
#pragma unroll
    for (int off = 1; off < 16; off <<= 1) t += __shfl_xor(t, off);
    sm[r] = t;
  }
  if (lc == 0)
#pragma unroll
    for (int r = 0; r < 4; ++r) red[1][w][quad * 4 + r] = sm[r];
  __syncthreads();
#pragma unroll
  for (int r = 0; r < 4; ++r) {
    const int row = quad * 4 + r;
    inv[r] = 1.f / (red[1][0][row] + red[1][1][row] + red[1][2][row] + red[1][3][row]);
  }
#pragma unroll
  for (int kt = 0; kt < 16; ++kt)
#pragma unroll
    for (int r = 0; r < 4; ++r)
      P[(quad * 4 + r) * 1032 + kt * 64 + w * 16 + lc] = f2us(s[kt][r] * inv[r]);
  __syncthreads();
  const us16* Vb = Vt + (size_t)(b * H_ + h) * DK_ * L_;
  f32x4 oacc = {};
  for (int kv = 0; kv < L_; kv += 32) {
    bf16x8 pa = *(const bf16x8*)&P[lc * 1032 + kv + quad * 8];
    bf16x8 vb = *(const bf16x8*)(Vb + (size_t)(w * 16 + lc) * L_ + kv + quad * 8);
    oacc = MFMA(pa, vb, oacc);
  }
#pragma unroll
  for (int r = 0; r < 4; ++r)
    O[(size_t)(b * L_ + q0 + quad * 4 + r) * D_ + h * DK_ + w * 16 + lc] =
        f2us(oacc[r]);
}

extern "C" void kernel_launch(void* const* d_in, const int* in_sizes, int n_in,
                              void* d_out, int out_size, void* d_ws, size_t ws_size,
                              hipStream_t stream) {
  const float* query   = (const float*)d_in[0];
  const float* key     = (const float*)d_in[1];
  const float* value   = (const float*)d_in[2];
  const float* wq_w    = (const float*)d_in[3];
  const float* wq_b    = (const float*)d_in[4];
  const float* wk_w    = (const float*)d_in[5];
  const float* wk_b    = (const float*)d_in[6];
  const float* wv_w    = (const float*)d_in[7];
  const float* wv_b    = (const float*)d_in[8];
  const float* dense_w = (const float*)d_in[9];
  const float* dense_b = (const float*)d_in[10];
  const float* gate_w  = (const float*)d_in[11];
  const float* gate_b  = (const float*)d_in[12];
  const float* mp_wq_w = (const float*)d_in[13];
  const float* mp_wq_b = (const float*)d_in[14];
  const float* mp_wk_w = (const float*)d_in[15];
  const float* mp_wk_b = (const float*)d_in[16];

  const size_t RSZ = (size_t)BL_ * D_;   // 2,097,152 elems
  const size_t WSZ = (size_t)D_ * D_;    // 262,144 elems
  us16* R0 = (us16*)d_ws;                // 4 MB
  us16* R1 = R0 + RSZ;                   // 4 MB

  float* out0 = (float*)d_out;                 // final out f32 (8 MB)
  float* outm = out0 + (size_t)B_ * L_ * D_;   // m f32 (16 MB)
  us16*  Vt   = (us16*)d_out;                  // V^T bf16 in out bytes [0,4M)
  float* gbuf = (float*)((char*)d_out + (4u << 20));

  dim3 blk(256);
  dim3 gattn(L_ / 16, H_, B_);

  if (ws_size >= ((size_t)20 << 20)) {
    // ws: R0(4M) R1(4M) Wt x6 (3M) Wk (8M) = 19 MB
    us16* Wt0 = R1 + RSZ;
    us16* mpq_t = Wt0;
    us16* mpk_t = Wt0 + WSZ;
    us16* wq_t  = Wt0 + 2 * WSZ;
    us16* wk_t  = Wt0 + 3 * WSZ;
    us16* wv_t  = Wt0 + 4 * WSZ;
    us16* dw_t  = Wt0 + 5 * WSZ;
    us16* Wk    = Wt0 + 6 * WSZ;   // 8 MB

    WT6 wt;
    wt.src[0] = mp_wq_w; wt.dst[0] = mpq_t;
    wt.src[1] = mp_wk_w; wt.dst[1] = mpk_t;
    wt.src[2] = wq_w;    wt.dst[2] = wq_t;
    wt.src[3] = wk_w;    wt.dst[3] = wk_t;
    wt.src[4] = wv_w;    wt.dst[4] = wv_t;
    wt.src[5] = dense_w; wt.dst[5] = dw_t;
    hipLaunchKernelGGL(wtrans6, dim3(8, 8, 6), blk, 0, stream, wt);
    hipLaunchKernelGGL(gate_kernel, dim3(BL_ / 4), blk, 0, stream, query, gate_w, gate_b, gbuf);

    GJobs mp;
    mp.j[0] = { query, mpq_t, mp_wq_b, R0, 0 };
    mp.j[1] = { key,   mpk_t, mp_wk_b, R1, 0 };
    mp.j[2] = mp.j[1];
    hipLaunchKernelGGL(gemm3, dim3(8, 64, 2), blk, 0, stream, mp);
    hipLaunchKernelGGL(mask16<true>, dim3(16, 16, B_), blk, 0, stream,
                       R0, R1, outm, gbuf, Wk);

    GJobs qkv;
    qkv.j[0] = { query, wq_t, wq_b, R0, 0 };
    qkv.j[1] = { key,   wk_t, wk_b, R1, 0 };
    qkv.j[2] = { value, wv_t, wv_b, Vt, 1 };
    hipLaunchKernelGGL(gemm3, dim3(8, 64, 3), blk, 0, stream, qkv);

    hipLaunchKernelGGL(attn3, gattn, blk, 0, stream, R0, R1, Vt, Wk, R0);
    hipLaunchKernelGGL(gemm_dense, dim3(8, 64), blk, 0, stream, R0, dw_t, dense_b, out0);
  } else {
    // -------- fallback (8 MB ws): round-8 structure --------
    dim3 gproj(8, 64);
    hipLaunchKernelGGL((gemm16<0, float>), gproj, blk, 0, stream, query, mp_wq_w, mp_wq_b, (void*)R0);
    hipLaunchKernelGGL((gemm16<0, float>), gproj, blk, 0, stream, key,   mp_wk_w, mp_wk_b, (void*)R1);
    hipLaunchKernelGGL(mask16<false>, dim3(16, 16, B_), blk, 0, stream,
                       R0, R1, outm, (const float*)nullptr, (us16*)nullptr);
    hipLaunchKernelGGL((gemm16<0, float>), gproj, blk, 0, stream, query, wq_w, wq_b, (void*)R0);
    hipLaunchKernelGGL((gemm16<0, float>), gproj, blk, 0, stream, key,   wk_w, wk_b, (void*)R1);
    hipLaunchKernelGGL((gemm16<1, float>), gproj, blk, 0, stream, value, wv_w, wv_b, (void*)Vt);
    hipLaunchKernelGGL(gate_kernel, dim3(BL_ / 4), blk, 0, stream, query, gate_w, gate_b, gbuf);
    hipLaunchKernelGGL(attn2_fb, gattn, blk, 0, stream, R0, R1, Vt, outm, gbuf, R0);
    hipLaunchKernelGGL((gemm16<2, us16>), gproj, blk, 0, stream, R0, dense_w, dense_b, (void*)out0);
  }
}